// Round 6
// baseline (116.806 us; speedup 1.0000x reference)
//
#include <hip/hip_runtime.h>

// NodeEncoder with interpolation, round 6.
//
// R5 (109.6 us, 4.97 TB/s) phase-separated reads/writes but pays a full
// vmcnt(0) store-drain at every __syncthreads (16 KB per drain). The barrier
// only exists to broadcast z through block LDS.
//
// R6: barrier-free wave-private structure. Per wave-iteration:
//   - lane i loads z[abase+i]        (one coalesced 256 B global load)
//   - 4 stores x 1 KB cover the wave's contiguous 4 KB output run;
//     the z each lane needs for store s is pulled with one __shfl
//     (lane (s<<4)+(lane>>2)) -- LDS pipe, no barrier.
// No __syncthreads in the hot loop -> stores never drain until kernel end,
// iterations fully independent (deep natural MLP).

#define K_TAB 16
#define N_Z   83
#define BLOCK 256

typedef float v4f __attribute__((ext_vector_type(4)));

__global__ __launch_bounds__(BLOCK) void node_encode_kernel(
    const float* __restrict__ z_in,
    float* __restrict__ out,
    int n_atoms)
{
    __shared__ float lut[N_Z][K_TAB];   // 5.3 KB, read-only after init

    const int tid = threadIdx.x;

    // ---- LUT init: threads 0..82 each build one row ----
    constexpr float tab[K_TAB] = {0.f, 1.f, 6.f, 7.f, 8.f, 11.f, 13.f, 14.f,
                                  16.f, 17.f, 26.f, 29.f, 47.f, 78.f, 79.f, 83.f};
    if (tid < N_Z) {
        const float zf = (float)tid;
        int j = 0;
        float zlo = tab[0];
        float zhi = tab[K_TAB - 1];
#pragma unroll
        for (int k = 0; k < K_TAB; ++k) {          // ascending: count < z, track z_lo
            const bool lt = (tab[k] < zf);
            j += lt ? 1 : 0;
            zlo = lt ? tab[k] : zlo;
        }
#pragma unroll
        for (int k = K_TAB - 2; k >= 0; --k) {     // descending: smallest entry >= z
            zhi = (tab[k] >= zf) ? tab[k] : zhi;
        }
        const bool exact = (zhi == zf);
        const float denom = exact ? 1.f : (zhi - zlo);
        const float inv   = 1.f / denom;
        const float whi   = exact ? 1.f : (zf - zlo) * inv;
        const float wlo   = exact ? 0.f : (zhi - zf) * inv;
        int jl = j - (exact ? 0 : 1);
        if (jl < 0) jl = 0;
#pragma unroll
        for (int c = 0; c < K_TAB; ++c) {
            lut[tid][c] = (c == j ? whi : 0.f) + (c == jl ? wlo : 0.f);
        }
    }
    __syncthreads();   // the ONLY barrier: LUT ready

    const int lane   = tid & 63;
    const int nwaves = gridDim.x * (BLOCK / 64);
    const int gwave  = blockIdx.x * (BLOCK / 64) + (tid >> 6);
    v4f* __restrict__ out4 = reinterpret_cast<v4f*>(out);

    const int niter = n_atoms >> 6;                // full 64-atom iterations
    for (int it = gwave; it < niter; it += nwaves) {
        const int abase = it << 6;
        const float zf  = z_in[abase + lane];      // coalesced 256 B per wave
        const int obase = abase << 2;              // float4 index of row start
#pragma unroll
        for (int s = 0; s < 4; ++s) {
            // z for the atom this lane writes in store s
            const float zs = __shfl(zf, (s << 4) + (lane >> 2), 64);
            const int   zi = (int)zs;
            const v4f   v  = *reinterpret_cast<const v4f*>(&lut[zi][(lane & 3) << 2]);
            out4[obase + (s << 6) + lane] = v;     // contiguous 1 KB per wave-store
        }
    }

    // tail (n_atoms % 64): negligible; one wave handles it scalar-wise
    const int rem_base = niter << 6;
    if (gwave == 0 && rem_base < n_atoms) {
        const int a = rem_base + lane;
        if (a < n_atoms) {
            const int zi = (int)z_in[a];
#pragma unroll
            for (int c = 0; c < 4; ++c)
                out4[a * 4 + c] = *reinterpret_cast<const v4f*>(&lut[zi][c << 2]);
        }
    }
}

extern "C" void kernel_launch(void* const* d_in, const int* in_sizes, int n_in,
                              void* d_out, int out_size, void* d_ws, size_t ws_size,
                              hipStream_t stream) {
    const float* z = (const float*)d_in[0];
    float* out = (float*)d_out;
    const int n_atoms = in_sizes[0];

    node_encode_kernel<<<2048, BLOCK, 0, stream>>>(z, out, n_atoms);
}

// Round 7
// 110.238 us; speedup vs baseline: 1.0596x; 1.0596x over previous
//
#include <hip/hip_runtime.h>

// NodeEncoder with interpolation, round 7.
//
// Base = R5 (109.6 us, 4.97 TB/s): phase-separated chunks, z staged via LDS,
// next chunk's z-load prefetched under the store phase.
//
// R7 change: remove the store-drain tax. __syncthreads forces
// s_waitcnt vmcnt(0) (drains up to 16 KB of outstanding stores per block,
// twice per phase). The barrier only needs to order LDS traffic. So:
//   - double-buffered zbuf  -> ONE barrier per phase (WAR separated by 2)
//   - raw s_barrier with lgkmcnt(0)-only wait (+ sched_barrier, "memory")
//     -> global stores never drain until kernel end; compiler inserts the
//     minimal counted vmcnt for the prefetched z register (T4 semantics).
//   - balanced grid: 1954 blocks x exactly ~4 chunks (R5 was 4-vs-3 mixed).

#define K_TAB 16
#define N_Z   83
#define CHUNK 1024                 // atoms per phase (4 KB z, 256 KB out)
#define BLOCK 256
#define INNER (CHUNK * 4 / BLOCK)  // float4 stores per thread per phase = 16

typedef float v4f __attribute__((ext_vector_type(4)));

// Barrier that orders LDS ops only — does NOT drain outstanding global stores.
__device__ __forceinline__ void lds_only_barrier() {
    __asm__ volatile("s_waitcnt lgkmcnt(0)" ::: "memory");
    __builtin_amdgcn_s_barrier();
    __builtin_amdgcn_sched_barrier(0);
}

__device__ __forceinline__ v4f load_chunk_z(const float* __restrict__ z_in,
                                            int c, int tid, int n_atoms) {
    const int a0 = c * CHUNK + tid * 4;
    v4f r = {0.f, 0.f, 0.f, 0.f};
    if (a0 + 3 < n_atoms) {
        r = *reinterpret_cast<const v4f*>(&z_in[a0]);
    } else {
#pragma unroll
        for (int e = 0; e < 4; ++e)
            if (a0 + e < n_atoms) r[e] = z_in[a0 + e];
    }
    return r;   // OOB atoms -> 0 -> lut row 0 (stores to them are guarded off)
}

__global__ __launch_bounds__(BLOCK) void node_encode_kernel(
    const float* __restrict__ z_in,
    float* __restrict__ out,
    int n_atoms, int n_chunks)
{
    __shared__ float lut[N_Z][K_TAB];   // 5.3 KB, read-only after init
    __shared__ float zbuf[2][CHUNK];    // 2 x 4 KB double buffer

    const int tid = threadIdx.x;

    // ---- LUT init: threads 0..82 each build one row ----
    constexpr float tab[K_TAB] = {0.f, 1.f, 6.f, 7.f, 8.f, 11.f, 13.f, 14.f,
                                  16.f, 17.f, 26.f, 29.f, 47.f, 78.f, 79.f, 83.f};
    if (tid < N_Z) {
        const float zf = (float)tid;
        int j = 0;
        float zlo = tab[0];
        float zhi = tab[K_TAB - 1];
#pragma unroll
        for (int k = 0; k < K_TAB; ++k) {          // ascending: count < z, track z_lo
            const bool lt = (tab[k] < zf);
            j += lt ? 1 : 0;
            zlo = lt ? tab[k] : zlo;
        }
#pragma unroll
        for (int k = K_TAB - 2; k >= 0; --k) {     // descending: smallest entry >= z
            zhi = (tab[k] >= zf) ? tab[k] : zhi;
        }
        const bool exact = (zhi == zf);
        const float denom = exact ? 1.f : (zhi - zlo);
        const float inv   = 1.f / denom;
        const float whi   = exact ? 1.f : (zf - zlo) * inv;
        const float wlo   = exact ? 0.f : (zhi - zf) * inv;
        int jl = j - (exact ? 0 : 1);
        if (jl < 0) jl = 0;
#pragma unroll
        for (int c = 0; c < K_TAB; ++c) {
            lut[tid][c] = (c == j ? whi : 0.f) + (c == jl ? wlo : 0.f);
        }
    }

    v4f* __restrict__ out4 = reinterpret_cast<v4f*>(out);
    const int total4 = n_atoms * 4;

    // ---- prologue: stage first chunk into zbuf[0] (also publishes LUT) ----
    int c = blockIdx.x;
    if (c < n_chunks) {
        const v4f z0 = load_chunk_z(z_in, c, tid, n_atoms);
        *reinterpret_cast<v4f*>(&zbuf[0][tid * 4]) = z0;  // compiler waits vmcnt for z0
    }
    lds_only_barrier();

    // ---- phase loop: one lgkm-only barrier per phase, stores never drain ----
    int p = 0;
    for (; c < n_chunks; c += gridDim.x, ++p) {
        const int cn = c + gridDim.x;
        const bool haveN = (cn < n_chunks);
        v4f zregN = {0.f, 0.f, 0.f, 0.f};
        if (haveN) zregN = load_chunk_z(z_in, cn, tid, n_atoms);  // issue early

        const float* __restrict__ zb = zbuf[p & 1];
        const int base4 = c * (CHUNK * 4);
        if (base4 + CHUNK * 4 <= total4) {
#pragma unroll
            for (int k = 0; k < INNER; ++k) {
                const int u  = k * BLOCK + tid;
                const int zi = (int)zb[u >> 2];
                const v4f v  = *reinterpret_cast<const v4f*>(&lut[zi][(u & 3) << 2]);
                out4[base4 + u] = v;
            }
        } else {
            for (int k = 0; k < INNER; ++k) {
                const int u = k * BLOCK + tid;
                const int g = base4 + u;
                if (g < total4) {
                    const int zi = (int)zb[u >> 2];
                    out4[g] = *reinterpret_cast<const v4f*>(&lut[zi][(u & 3) << 2]);
                }
            }
        }

        if (haveN) {
            // compiler inserts counted vmcnt for zregN (stores stay in flight)
            *reinterpret_cast<v4f*>(&zbuf[(p + 1) & 1][tid * 4]) = zregN;
        }
        lds_only_barrier();
    }
}

extern "C" void kernel_launch(void* const* d_in, const int* in_sizes, int n_in,
                              void* d_out, int out_size, void* d_ws, size_t ws_size,
                              hipStream_t stream) {
    const float* z = (const float*)d_in[0];
    float* out = (float*)d_out;
    const int n_atoms = in_sizes[0];

    const int n_chunks = (n_atoms + CHUNK - 1) / CHUNK;        // 7813
    const int phases   = 4;                                     // target chunks/block
    int grid = (n_chunks + phases - 1) / phases;                // 1954, balanced
    if (grid > 2048) grid = 2048;

    node_encode_kernel<<<grid, BLOCK, 0, stream>>>(z, out, n_atoms, n_chunks);
}